// Round 2
// baseline (536.454 us; speedup 1.0000x reference)
//
#include <hip/hip_runtime.h>
#include <math.h>

#define B_    8
#define Q_    900
#define NCLS_ 11
#define NANC_ 100
#define H_    200
#define W_    200
#define C_    256
#define ROWS_ 4            // rows (one wave each) per bev block

// ---------------------------------------------------------------------------
// Kernel 1: scores + rank-based top-k + box->pixel coords (one block per batch)
// ---------------------------------------------------------------------------
__global__ __launch_bounds__(1024) void segdet_topk_kernel(
    const float* __restrict__ pred_boxes,   // [B,Q,4]
    const float* __restrict__ pred_logits,  // [B,Q,NCLS]
    const float* __restrict__ view,         // [B,5,5]
    int*  __restrict__ ws_idx,              // [B,NANC]  selected q index
    int4* __restrict__ ws_box)              // [B,NANC]  (x0,y0,x1,y1) clipped ints
{
    const int b = blockIdx.x;
    const int q = threadIdx.x;

    __shared__ float sc[Q_];

    if (q < Q_) {
        const float* l = pred_logits + (b * Q_ + q) * NCLS_;
        float v[NCLS_];
        float m = -INFINITY;
        #pragma unroll
        for (int i = 0; i < NCLS_; ++i) { v[i] = l[i]; m = fmaxf(m, v[i]); }
        float s = 0.0f, e10 = -INFINITY;
        #pragma unroll
        for (int i = 0; i < NCLS_; ++i) {
            float e = expf(v[i] - m);
            s += e;
            if (i < NCLS_ - 1) e10 = fmaxf(e10, e);   // exclude background (last)
        }
        sc[q] = e10 / s;
    }
    __syncthreads();

    if (q < Q_) {
        const float my = sc[q];
        int rank = 0;
        for (int j = 0; j < Q_; ++j) {
            float o = sc[j];
            rank += (o > my) || (o == my && j < q);   // top_k tie-break: lower idx first
        }
        if (rank < NANC_) {
            // box -> xyxy -> view transform -> trunc int -> clip, in double so the
            // int-truncation boundary matches the reference exactly.
            const float* bx = pred_boxes + (b * Q_ + q) * 4;
            double cx = (double)bx[0], cy = (double)bx[1];
            double w  = exp((double)bx[2]);
            double h  = exp((double)bx[3]);
            double p[5] = { cx - 0.5 * w, cy - 0.5 * h,
                            cx + 0.5 * w, cy + 0.5 * h, 1.0 };
            const float* v5 = view + b * 25;
            int ico[4];
            #pragma unroll
            for (int i = 0; i < 4; ++i) {
                double acc = 0.0;
                #pragma unroll
                for (int j = 0; j < 5; ++j) acc += (double)v5[i * 5 + j] * p[j];
                ico[i] = (int)acc;                    // trunc toward zero == astype(int32)
            }
            int x0 = min(max(ico[0], 0), W_);
            int y0 = min(max(ico[1], 0), H_);
            int x1 = min(max(ico[2], 0), W_);
            int y1 = min(max(ico[3], 0), H_);
            const int slot = b * NANC_ + rank;        // rank unique -> no atomics
            ws_idx[slot] = q;
            ws_box[slot] = make_int4(x0, y0, x1, y1);
        }
    }
}

// ---------------------------------------------------------------------------
// Kernel 2: BEV splat, segment-run version.
// Block = 256 threads = 4 waves; each wave owns one (b,h) row.
// Lane owns 4 channels (float4). Per row: build 200-bit event bitmask via
// __ballot, then walk constant segments issuing back-to-back dwordx4 stores.
// ---------------------------------------------------------------------------
__global__ __launch_bounds__(256) void segdet_bev_kernel(
    const float* __restrict__ box_feats,    // [B,Q,C]
    const int*   __restrict__ ws_idx,       // [B,NANC]
    const int4*  __restrict__ ws_box,       // [B,NANC]
    float* __restrict__ bev,                // [B,H,W,C]
    float* __restrict__ mask)               // [B,H,W] (0/1 floats)
{
    const int b    = blockIdx.x / (H_ / ROWS_);
    const int hg   = blockIdx.x % (H_ / ROWS_);
    const int wave = threadIdx.x >> 6;
    const int lane = threadIdx.x & 63;
    const int h    = hg * ROWS_ + wave;

    __shared__ int4 s_box[NANC_];
    __shared__ int  s_qid[NANC_];
    __shared__ int  s_x0[ROWS_][NANC_];
    __shared__ int  s_x1[ROWS_][NANC_];
    __shared__ int  s_q [ROWS_][NANC_];

    if (threadIdx.x < NANC_) {
        s_box[threadIdx.x] = ws_box[b * NANC_ + threadIdx.x];
        s_qid[threadIdx.x] = ws_idx[b * NANC_ + threadIdx.x];
    }
    __syncthreads();

    // Per-wave compaction of row-active anchors (ballot+prefix: deterministic,
    // no serial section, order = anchor rank order).
    int nact = 0;
    #pragma unroll
    for (int it = 0; it < 2; ++it) {
        int k = it * 64 + lane;
        bool act = false;
        int4 bx = make_int4(0, 0, 0, 0);
        int  qi = 0;
        if (k < NANC_) {
            bx = s_box[k]; qi = s_qid[k];
            act = (bx.y <= h) && (h < bx.w) && (bx.x < bx.z);
        }
        unsigned long long ball = __ballot(act);
        int pos = nact + (int)__popcll(ball & ((1ull << lane) - 1ull));
        if (act) { s_x0[wave][pos] = bx.x; s_x1[wave][pos] = bx.z; s_q[wave][pos] = qi; }
        nact += (int)__popcll(ball);
    }
    __syncthreads();

    // 200-bit event bitmask (positions where any box starts or ends)
    unsigned long long em[4];
    #pragma unroll
    for (int wd = 0; wd < 4; ++wd) {
        int wpos = wd * 64 + lane;
        bool flag = false;
        if (wpos < W_) {
            for (int k = 0; k < nact; ++k)
                flag |= (s_x0[wave][k] == wpos) || (s_x1[wave][k] == wpos);
        }
        em[wd] = __ballot(flag);            // uniform across the wave
    }

    const float* fbase = box_feats + ((size_t)b * Q_) * C_ + lane * 4;
    float* orow = bev + ((size_t)(b * H_ + h) * W_) * C_ + lane * 4;
    float* mrow = mask + (size_t)(b * H_ + h) * W_;

    float4 acc = make_float4(0.f, 0.f, 0.f, 0.f);
    int cnt = 0;
    int cur = 0;
    while (cur < W_) {
        if ((em[cur >> 6] >> (cur & 63)) & 1ull) {
            for (int k = 0; k < nact; ++k) {
                int x0 = s_x0[wave][k], x1 = s_x1[wave][k];
                if (x0 == cur || x1 == cur) {
                    const float4 f = *(const float4*)(fbase + (size_t)s_q[wave][k] * C_);
                    if (x0 == cur) {
                        acc.x += f.x; acc.y += f.y; acc.z += f.z; acc.w += f.w; ++cnt;
                    } else {
                        acc.x -= f.x; acc.y -= f.y; acc.z -= f.z; acc.w -= f.w; --cnt;
                    }
                }
            }
            if (cnt == 0) acc = make_float4(0.f, 0.f, 0.f, 0.f);  // exact zeros
        }
        // next event position > cur (bits >= W_ are never set)
        int nxt;
        {
            int from = cur + 1;
            int wd = from >> 6;
            unsigned long long m = em[wd] & (~0ull << (from & 63));
            while (m == 0ull && ++wd < 4) m = em[wd];
            nxt = (wd < 4) ? (wd * 64 + (int)__ffsll((unsigned long long)m) - 1) : W_;
        }
        // constant segment [cur, nxt): back-to-back 1KB/wave dwordx4 stores
        for (int w = cur; w < nxt; ++w)
            *(float4*)(orow + (size_t)w * C_) = acc;
        float mval = (cnt > 0) ? 1.0f : 0.0f;
        for (int w = cur + lane; w < nxt; w += 64)
            mrow[w] = mval;
        cur = nxt;
    }
}

// ---------------------------------------------------------------------------
extern "C" void kernel_launch(void* const* d_in, const int* in_sizes, int n_in,
                              void* d_out, int out_size, void* d_ws, size_t ws_size,
                              hipStream_t stream) {
    const float* pred_boxes  = (const float*)d_in[0];
    const float* pred_logits = (const float*)d_in[1];
    const float* box_feats   = (const float*)d_in[2];
    const float* view        = (const float*)d_in[3];

    float* bev  = (float*)d_out;
    float* mask = bev + (size_t)B_ * H_ * W_ * C_;

    int*  ws_idx = (int*)d_ws;                            // 800 ints = 3200 B
    int4* ws_box = (int4*)((char*)d_ws + 3200);           // 800 int4 (16B aligned)

    segdet_topk_kernel<<<B_, 1024, 0, stream>>>(pred_boxes, pred_logits, view,
                                                ws_idx, ws_box);
    segdet_bev_kernel<<<B_ * (H_ / ROWS_), 256, 0, stream>>>(box_feats, ws_idx, ws_box,
                                                             bev, mask);
}

// Round 3
// 502.313 us; speedup vs baseline: 1.0680x; 1.0680x over previous
//
#include <hip/hip_runtime.h>
#include <math.h>

#define B_    8
#define Q_    900
#define NCLS_ 11
#define NANC_ 100
#define H_    200
#define W_    200
#define C_    256

// ---------------------------------------------------------------------------
// Kernel 1: scores + rank-based top-k + box->pixel coords (one block per batch)
// ---------------------------------------------------------------------------
__global__ __launch_bounds__(1024) void segdet_topk_kernel(
    const float* __restrict__ pred_boxes,   // [B,Q,4]
    const float* __restrict__ pred_logits,  // [B,Q,NCLS]
    const float* __restrict__ view,         // [B,5,5]
    int*  __restrict__ ws_idx,              // [B,NANC]  selected q index
    int4* __restrict__ ws_box)              // [B,NANC]  (x0,y0,x1,y1) clipped ints
{
    const int b = blockIdx.x;
    const int q = threadIdx.x;

    __shared__ float sc[Q_];

    if (q < Q_) {
        const float* l = pred_logits + (b * Q_ + q) * NCLS_;
        float v[NCLS_];
        float m = -INFINITY;
        #pragma unroll
        for (int i = 0; i < NCLS_; ++i) { v[i] = l[i]; m = fmaxf(m, v[i]); }
        float s = 0.0f, e10 = -INFINITY;
        #pragma unroll
        for (int i = 0; i < NCLS_; ++i) {
            float e = expf(v[i] - m);
            s += e;
            if (i < NCLS_ - 1) e10 = fmaxf(e10, e);   // exclude background (last)
        }
        sc[q] = e10 / s;
    }
    __syncthreads();

    if (q < Q_) {
        const float my = sc[q];
        int rank = 0;
        for (int j = 0; j < Q_; ++j) {
            float o = sc[j];
            rank += (o > my) || (o == my && j < q);   // top_k tie-break: lower idx first
        }
        if (rank < NANC_) {
            // box -> xyxy -> view transform -> trunc int -> clip, in double so the
            // int-truncation boundary matches the reference exactly.
            const float* bx = pred_boxes + (b * Q_ + q) * 4;
            double cx = (double)bx[0], cy = (double)bx[1];
            double w  = exp((double)bx[2]);
            double h  = exp((double)bx[3]);
            double p[5] = { cx - 0.5 * w, cy - 0.5 * h,
                            cx + 0.5 * w, cy + 0.5 * h, 1.0 };
            const float* v5 = view + b * 25;
            int ico[4];
            #pragma unroll
            for (int i = 0; i < 4; ++i) {
                double acc = 0.0;
                #pragma unroll
                for (int j = 0; j < 5; ++j) acc += (double)v5[i * 5 + j] * p[j];
                ico[i] = (int)acc;                    // trunc toward zero == astype(int32)
            }
            int x0 = min(max(ico[0], 0), W_);
            int y0 = min(max(ico[1], 0), H_);
            int x1 = min(max(ico[2], 0), W_);
            int y1 = min(max(ico[3], 0), H_);
            const int slot = b * NANC_ + rank;        // rank unique -> no atomics
            ws_idx[slot] = q;
            ws_box[slot] = make_int4(x0, y0, x1, y1);
        }
    }
}

// ---------------------------------------------------------------------------
// Kernel 2: BEV splat. One block per (b,h) row, 256 threads = 256 channels.
// Parallel build: wave-0 ballot-compacts row-active anchors; all threads build
// per-pixel event flags + coverage (mask) in parallel; block-scan compacts the
// ascending event-pixel list. Main loop: register-held next-event pixel,
// stores unrolled x4 — LDS/global reads only at the ~30 event pixels.
// No runtime-indexed private arrays anywhere (scratch-free).
// ---------------------------------------------------------------------------
__global__ __launch_bounds__(256) void segdet_bev_kernel(
    const float* __restrict__ box_feats,    // [B,Q,C]
    const int*   __restrict__ ws_idx,       // [B,NANC]
    const int4*  __restrict__ ws_box,       // [B,NANC]
    float* __restrict__ bev,                // [B,H,W,C]
    float* __restrict__ mask)               // [B,H,W] (0/1 floats)
{
    const int b = blockIdx.x / H_;
    const int h = blockIdx.x % H_;
    const int tid = threadIdx.x;
    const int ln  = tid & 63;
    const int wv  = tid >> 6;

    __shared__ int s_x0[NANC_];
    __shared__ int s_x1[NANC_];
    __shared__ int s_q [NANC_];
    __shared__ int s_nact;
    __shared__ int s_evpos[W_];
    __shared__ int s_wtot[4];
    __shared__ int s_nev;

    // ---- wave-0 ballot compaction of row-active anchors (deterministic order)
    if (tid < 64) {
        int na = 0;
        #pragma unroll
        for (int it = 0; it < 2; ++it) {
            int k = it * 64 + ln;
            bool act = false;
            int x0 = 0, x1 = 0, qi = 0;
            if (k < NANC_) {
                int4 bx = ws_box[b * NANC_ + k];
                qi = ws_idx[b * NANC_ + k];
                x0 = bx.x; x1 = bx.z;
                act = (bx.y <= h) && (h < bx.w) && (x0 < x1);
            }
            unsigned long long ball = __ballot(act);
            int pos = na + (int)__popcll(ball & ((1ull << ln) - 1ull));
            if (act) { s_x0[pos] = x0; s_x1[pos] = x1; s_q[pos] = qi; }
            na += (int)__popcll(ball);
        }
        if (ln == 0) s_nact = na;
    }
    __syncthreads();

    const int nact = s_nact;
    float* mrow = mask + (size_t)(b * H_ + h) * W_;

    // ---- per-pixel event flag + coverage (mask) in parallel; mask burst store
    bool flag = false;
    if (tid < W_) {
        int cov = 0;
        for (int k = 0; k < nact; ++k) {
            int x0 = s_x0[k], x1 = s_x1[k];
            flag |= (x0 == tid) || (x1 == tid);
            cov  += (x0 <= tid) && (tid < x1);
        }
        mrow[tid] = (cov > 0) ? 1.0f : 0.0f;
    }

    // ---- block-scan compaction of ascending event pixels
    unsigned long long bal = __ballot(flag);
    if (ln == 0) s_wtot[wv] = (int)__popcll(bal);
    __syncthreads();
    int off = 0;
    for (int i = 0; i < wv; ++i) off += s_wtot[i];
    if (flag) s_evpos[off + (int)__popcll(bal & ((1ull << ln) - 1ull))] = tid;
    if (tid == 0) s_nev = s_wtot[0] + s_wtot[1] + s_wtot[2] + s_wtot[3];
    __syncthreads();

    const int nev = s_nev;

    // ---- main loop: near-pure store stream, events applied at register-held wnext
    const float* fcol = box_feats + (size_t)b * Q_ * C_ + tid;
    float* orow = bev + ((size_t)(b * H_ + h) * W_) * C_ + tid;

    float acc = 0.0f;
    int cnt = 0;
    int p = 0;
    int wnext = (p < nev) ? s_evpos[p] : W_;
    int w = 0;
    while (w < W_) {
        if (w == wnext) {
            for (int k = 0; k < nact; ++k) {
                int x0 = s_x0[k], x1 = s_x1[k];
                if (x0 == w) {
                    acc += fcol[(size_t)s_q[k] * C_]; ++cnt;
                } else if (x1 == w) {
                    acc -= fcol[(size_t)s_q[k] * C_]; --cnt;
                }
            }
            if (cnt == 0) acc = 0.0f;       // exact zeros outside coverage
            ++p;
            wnext = (p < nev) ? s_evpos[p] : W_;
        }
        const int end = (wnext < W_) ? wnext : W_;
        float* po = orow + (size_t)w * C_;
        for (; w + 4 <= end; w += 4) {      // offsets 0/1/2/3 KB fold into stores
            po[0 * C_] = acc;
            po[1 * C_] = acc;
            po[2 * C_] = acc;
            po[3 * C_] = acc;
            po += 4 * C_;
        }
        for (; w < end; ++w) { *po = acc; po += C_; }
    }
}

// ---------------------------------------------------------------------------
extern "C" void kernel_launch(void* const* d_in, const int* in_sizes, int n_in,
                              void* d_out, int out_size, void* d_ws, size_t ws_size,
                              hipStream_t stream) {
    const float* pred_boxes  = (const float*)d_in[0];
    const float* pred_logits = (const float*)d_in[1];
    const float* box_feats   = (const float*)d_in[2];
    const float* view        = (const float*)d_in[3];

    float* bev  = (float*)d_out;
    float* mask = bev + (size_t)B_ * H_ * W_ * C_;

    int*  ws_idx = (int*)d_ws;                            // 800 ints = 3200 B
    int4* ws_box = (int4*)((char*)d_ws + 3200);           // 800 int4 (16B aligned)

    segdet_topk_kernel<<<B_, 1024, 0, stream>>>(pred_boxes, pred_logits, view,
                                                ws_idx, ws_box);
    segdet_bev_kernel<<<B_ * H_, 256, 0, stream>>>(box_feats, ws_idx, ws_box,
                                                   bev, mask);
}

// Round 4
// 112.020 us; speedup vs baseline: 4.7889x; 4.4841x over previous
//
#include <hip/hip_runtime.h>
#include <math.h>

#define B_    8
#define Q_    900
#define NCLS_ 11
#define NANC_ 100
#define H_    200
#define W_    200
#define C_    256

// ---------------------------------------------------------------------------
// Kernel 1: scores + rank-based top-k + box->pixel coords (one block per batch)
// ---------------------------------------------------------------------------
__global__ __launch_bounds__(1024) void segdet_topk_kernel(
    const float* __restrict__ pred_boxes,   // [B,Q,4]
    const float* __restrict__ pred_logits,  // [B,Q,NCLS]
    const float* __restrict__ view,         // [B,5,5]
    int*  __restrict__ ws_idx,              // [B,NANC]  selected q index
    int4* __restrict__ ws_box)              // [B,NANC]  (x0,y0,x1,y1) clipped ints
{
    const int b = blockIdx.x;
    const int q = threadIdx.x;

    __shared__ float sc[Q_];

    if (q < Q_) {
        const float* l = pred_logits + (b * Q_ + q) * NCLS_;
        float v[NCLS_];
        float m = -INFINITY;
        #pragma unroll
        for (int i = 0; i < NCLS_; ++i) { v[i] = l[i]; m = fmaxf(m, v[i]); }
        float s = 0.0f, e10 = -INFINITY;
        #pragma unroll
        for (int i = 0; i < NCLS_; ++i) {
            float e = expf(v[i] - m);
            s += e;
            if (i < NCLS_ - 1) e10 = fmaxf(e10, e);   // exclude background (last)
        }
        sc[q] = e10 / s;
    }
    __syncthreads();

    if (q < Q_) {
        const float my = sc[q];
        int rank = 0;
        for (int j = 0; j < Q_; ++j) {
            float o = sc[j];
            rank += (o > my) || (o == my && j < q);   // top_k tie-break: lower idx first
        }
        if (rank < NANC_) {
            // box -> xyxy -> view transform -> trunc int -> clip, in double so the
            // int-truncation boundary matches the reference exactly.
            const float* bx = pred_boxes + (b * Q_ + q) * 4;
            double cx = (double)bx[0], cy = (double)bx[1];
            double w  = exp((double)bx[2]);
            double h  = exp((double)bx[3]);
            double p[5] = { cx - 0.5 * w, cy - 0.5 * h,
                            cx + 0.5 * w, cy + 0.5 * h, 1.0 };
            const float* v5 = view + b * 25;
            int ico[4];
            #pragma unroll
            for (int i = 0; i < 4; ++i) {
                double acc = 0.0;
                #pragma unroll
                for (int j = 0; j < 5; ++j) acc += (double)v5[i * 5 + j] * p[j];
                ico[i] = (int)acc;                    // trunc toward zero == astype(int32)
            }
            int x0 = min(max(ico[0], 0), W_);
            int y0 = min(max(ico[1], 0), H_);
            int x1 = min(max(ico[2], 0), W_);
            int y1 = min(max(ico[3], 0), H_);
            const int slot = b * NANC_ + rank;        // rank unique -> no atomics
            ws_idx[slot] = q;
            ws_box[slot] = make_int4(x0, y0, x1, y1);
        }
    }
}

// ---------------------------------------------------------------------------
// Kernel 2: BEV splat, CSR-event version.
// One block per (b,h) row, 256 threads = 4 waves. Lane owns 4 channels
// (float4 => 1KB per wave-store); wave wv owns pixels {wv, wv+4, ...} with a
// private register accumulator, applying CSR events as it passes them.
// Event application is O(2*nact) per wave (was O(nev*nact) — the round-3
// killer on Gaussian-centered rows with nact~60, nev~100).
// No runtime-indexed private arrays (scratch-free).
// ---------------------------------------------------------------------------
__global__ __launch_bounds__(256) void segdet_bev_kernel(
    const float* __restrict__ box_feats,    // [B,Q,C]
    const int*   __restrict__ ws_idx,       // [B,NANC]
    const int4*  __restrict__ ws_box,       // [B,NANC]
    float* __restrict__ bev,                // [B,H,W,C]
    float* __restrict__ mask)               // [B,H,W] (0/1 floats)
{
    const int b   = blockIdx.x / H_;
    const int h   = blockIdx.x % H_;
    const int tid = threadIdx.x;
    const int ln  = tid & 63;
    const int wv  = tid >> 6;

    __shared__ int s_box[NANC_];            // x0 | x1<<8 | q<<16 (packed)
    __shared__ int s_nact;
    __shared__ int s_nopen[W_];             // # opens at pixel w
    __shared__ int s_scan[256];             // scan workspace
    __shared__ int s_ofs[W_ + 1];           // CSR offsets (exclusive scan)
    __shared__ int s_evpos[W_];             // ascending event pixels
    __shared__ int s_ent[2 * NANC_];        // CSR entries: q | (close ? 1<<31 : 0)
    __shared__ int s_wtot[4];
    __shared__ int s_nev;

    // ---- wave-0 ballot compaction of row-active anchors (deterministic order)
    if (tid < 64) {
        int na = 0;
        #pragma unroll
        for (int it = 0; it < 2; ++it) {
            int k = it * 64 + ln;
            bool act = false;
            int packed = 0;
            if (k < NANC_) {
                int4 bx = ws_box[b * NANC_ + k];
                int qi  = ws_idx[b * NANC_ + k];
                act = (bx.y <= h) && (h < bx.w) && (bx.x < bx.z);
                packed = bx.x | (bx.z << 8) | (qi << 16);
            }
            unsigned long long ball = __ballot(act);
            int pos = na + (int)__popcll(ball & ((1ull << ln) - 1ull));
            if (act) s_box[pos] = packed;
            na += (int)__popcll(ball);
        }
        if (ln == 0) s_nact = na;
    }
    __syncthreads();

    const int nact = s_nact;

    // ---- per-pixel open/close counts + coverage (mask), in parallel
    int ntot = 0;
    if (tid < W_) {
        int nopen = 0, nclose = 0, cov = 0;
        for (int k = 0; k < nact; ++k) {
            int pk = s_box[k];                 // uniform LDS broadcast
            int x0 = pk & 0xFF, x1 = (pk >> 8) & 0xFF;
            nopen  += (x0 == tid);
            nclose += (x1 == tid);             // x1==200 auto-excluded (tid<200)
            cov    += (x0 <= tid) && (tid < x1);
        }
        s_nopen[tid] = nopen;
        ntot = nopen + nclose;
        mask[(size_t)(b * H_ + h) * W_ + tid] = (cov > 0) ? 1.0f : 0.0f;
    }
    s_scan[tid] = ntot;
    __syncthreads();

    // ---- Hillis-Steele inclusive scan over 256 entries
    #pragma unroll
    for (int d = 1; d < 256; d <<= 1) {
        int v = s_scan[tid];
        int u = (tid >= d) ? s_scan[tid - d] : 0;
        __syncthreads();
        s_scan[tid] = v + u;
        __syncthreads();
    }
    if (tid < W_) s_ofs[tid] = s_scan[tid] - ntot;   // exclusive scan
    if (tid == 0) s_ofs[W_] = s_scan[255];           // total entries

    // ---- event-pixel compaction (ascending order, ballot+prefix)
    bool flag = (tid < W_) && (ntot > 0);
    unsigned long long bal = __ballot(flag);
    if (ln == 0) s_wtot[wv] = (int)__popcll(bal);
    __syncthreads();
    int off = 0;
    for (int i = 0; i < wv; ++i) off += s_wtot[i];
    if (flag) s_evpos[off + (int)__popcll(bal & ((1ull << ln) - 1ull))] = tid;
    if (tid == 0) s_nev = s_wtot[0] + s_wtot[1] + s_wtot[2] + s_wtot[3];

    // ---- CSR entry scatter: one thread per active box, stable k-order
    if (tid < nact) {
        int pk = s_box[tid];
        int x0 = pk & 0xFF, x1 = (pk >> 8) & 0xFF, q = pk >> 16;
        int ro = 0, rc = 0;
        for (int j = 0; j < tid; ++j) {
            int pj = s_box[j];
            ro += ((pj & 0xFF) == x0);
            rc += (((pj >> 8) & 0xFF) == x1);
        }
        s_ent[s_ofs[x0] + ro] = q;                                        // open
        if (x1 < W_) s_ent[s_ofs[x1] + s_nopen[x1] + rc] = q | (1 << 31); // close
    }
    __syncthreads();

    // ---- main loop: wave wv owns pixels wv, wv+4, ... ; 1KB float4 stores
    const int nev = s_nev;
    const float* fbase = box_feats + (size_t)b * Q_ * C_ + ln * 4;
    float* obase = bev + (size_t)(b * H_ + h) * W_ * C_ + ln * 4;

    float4 acc = make_float4(0.f, 0.f, 0.f, 0.f);
    int cnt = 0;
    int p = 0;
    int nextpix = (0 < nev) ? s_evpos[0] : W_;       // register-held next event
    for (int w = wv; w < W_; w += 4) {
        while (w >= nextpix) {                        // apply events passed
            int e1 = s_ofs[nextpix + 1];
            for (int e = s_ofs[nextpix]; e < e1; ++e) {
                int ent = s_ent[e];                   // uniform broadcast
                int q = ent & 0xFFFF;
                const float4 f = *(const float4*)(fbase + (size_t)q * C_);
                if (ent < 0) { acc.x -= f.x; acc.y -= f.y; acc.z -= f.z; acc.w -= f.w; --cnt; }
                else         { acc.x += f.x; acc.y += f.y; acc.z += f.z; acc.w += f.w; ++cnt; }
            }
            ++p;
            nextpix = (p < nev) ? s_evpos[p] : W_;
        }
        if (cnt == 0) acc = make_float4(0.f, 0.f, 0.f, 0.f);  // exact zeros
        *(float4*)(obase + (size_t)w * C_) = acc;
    }
}

// ---------------------------------------------------------------------------
extern "C" void kernel_launch(void* const* d_in, const int* in_sizes, int n_in,
                              void* d_out, int out_size, void* d_ws, size_t ws_size,
                              hipStream_t stream) {
    const float* pred_boxes  = (const float*)d_in[0];
    const float* pred_logits = (const float*)d_in[1];
    const float* box_feats   = (const float*)d_in[2];
    const float* view        = (const float*)d_in[3];

    float* bev  = (float*)d_out;
    float* mask = bev + (size_t)B_ * H_ * W_ * C_;

    int*  ws_idx = (int*)d_ws;                            // 800 ints = 3200 B
    int4* ws_box = (int4*)((char*)d_ws + 3200);           // 800 int4 (16B aligned)

    segdet_topk_kernel<<<B_, 1024, 0, stream>>>(pred_boxes, pred_logits, view,
                                                ws_idx, ws_box);
    segdet_bev_kernel<<<B_ * H_, 256, 0, stream>>>(box_feats, ws_idx, ws_box,
                                                   bev, mask);
}